// Round 2
// baseline (2268.790 us; speedup 1.0000x reference)
//
#include <hip/hip_runtime.h>
#include <hip/hip_bf16.h>

#define DT 0.01f

// sin(x) with Cody-Waite reduction mod pi, accurate to ~2e-7 for |x| < ~6000.
__device__ __forceinline__ float fast_sin(float x) {
  const float INVPI = 0.3183098861837907f;
  float n = rintf(x * INVPI);
  int ni = (int)n;
  float r = fmaf(n, -3.140625f, x);          // n*3.140625 exact for |n| < 2^12
  r = fmaf(n, -9.6765358979e-4f, r);         // pi - 3.140625
  float s = r * r;
  float p = fmaf(s, -2.5052108e-8f, 2.7557319e-6f);
  p = fmaf(s, p, -1.9841270e-4f);
  p = fmaf(s, p, 8.3333333e-3f);
  p = fmaf(s, p, -1.6666667e-1f);
  float res = fmaf(r * s, p, r);             // sin(r), |r| <= pi/2
  return (ni & 1) ? -res : res;              // sin(x) = (-1)^n sin(r)
}

// K0s[h,j] = sum_m k0[h,m,j]   (k0: [128,512,512])
__global__ __launch_bounds__(256) void kPrep1(const float* __restrict__ k0,
                                              float* __restrict__ K0s) {
  int t = blockIdx.x * 256 + threadIdx.x;     // 65536 threads
  int h = t >> 9, j = t & 511;
  const float* p = k0 + (size_t)h * 262144 + j;
  float s = 0.f;
  for (int m = 0; m < 512; ++m) s += p[(size_t)m * 512];
  K0s[t] = s;
}

// K1s[h,j] = sum_m k1[h,m,j]   (k1: [128,512,128])
__global__ __launch_bounds__(256) void kPrep2(const float* __restrict__ k1,
                                              float* __restrict__ K1s) {
  int t = blockIdx.x * 256 + threadIdx.x;     // 16384 threads
  int h = t >> 7, j = t & 127;
  const float* p = k1 + (size_t)h * 65536 + j;
  float s = 0.f;
  for (int m = 0; m < 512; ++m) s += p[(size_t)m * 128];
  K1s[t] = s;
}

// M[l,j] = sum_h K1s[l,h] * K0s[h,j]   ([128,512] = K1s @ K0s)
__global__ __launch_bounds__(256) void kPrep3(const float* __restrict__ K0s,
                                              const float* __restrict__ K1s,
                                              float* __restrict__ M) {
  int t = blockIdx.x * 256 + threadIdx.x;     // 65536 threads
  int l = t >> 9, j = t & 511;
  float s = 0.f;
#pragma unroll 8
  for (int h = 0; h < 128; ++h) s = fmaf(K1s[l * 128 + h], K0s[h * 512 + j], s);
  M[t] = s;
}

// Kernel A: RK4 bookkeeping + s2 = M * y_stage.
// Grid 64 WGs x 256: WG = (b = blk>>2, quarter q = blk&3).
// stage: 0 = init (y = y0), 1..4 = RK stages. y ping-pongs on step parity.
__global__ __launch_bounds__(256) void kA(
    const float* __restrict__ y0, const float* __restrict__ bias,
    const float* __restrict__ M, const float* __restrict__ aggp,
    float* __restrict__ ybuf,    // [2][16][512]
    float* __restrict__ racc,    // [16][512]
    float* __restrict__ s2,      // [16][128]
    float* __restrict__ out,     // [8][16][512]
    int stage, int step) {
  __shared__ float ystage[512];
  __shared__ float red[256];
  const int b = blockIdx.x >> 2, q = blockIdx.x & 3, t = threadIdx.x;
  const float* ycur = ybuf + (step & 1) * 8192;
  float* ynext = ybuf + ((step + 1) & 1) * 8192;

  for (int i = t; i < 512; i += 256) {
    const int idx = b * 512 + i;
    const bool own = (i >> 7) == q;   // this WG owns chunk q of row b
    float ys;
    if (stage == 0) {
      ys = y0[idx];
      if (own) ynext[idx] = ys;       // init writes ybuf[0] (step = -1)
    } else {
      const float r = bias[idx] - (aggp[idx] + aggp[8192 + idx]);
      const float yb = ycur[idx];
      if (stage == 1) {
        ys = fmaf(0.5f * DT, r, yb);
        if (own) racc[idx] = r;
      } else if (stage == 2) {
        ys = fmaf(0.5f * DT, r, yb);
        if (own) racc[idx] = racc[idx] + 2.f * r;
      } else if (stage == 3) {
        ys = fmaf(DT, r, yb);
        if (own) racc[idx] = racc[idx] + 2.f * r;
      } else {  // stage 4: finish step
        ys = yb + (DT / 6.f) * (racc[idx] + r);
        if (own) { ynext[idx] = ys; out[step * 8192 + idx] = ys; }
      }
    }
    ystage[i] = ys;
  }
  __syncthreads();

  // s2[b, l] for l in [q*32, q*32+32): 8 threads per dot, 64 j each.
  const int l = q * 32 + (t >> 3), seg = t & 7;
  const float* Mrow = M + l * 512 + seg * 64;
  float p = 0.f;
#pragma unroll 8
  for (int i = 0; i < 64; ++i) p = fmaf(Mrow[i], ystage[seg * 64 + i], p);
  red[t] = p;
  __syncthreads();
  if (seg == 0) {
    float ssum = 0.f;
#pragma unroll
    for (int k = 0; k < 8; ++k) ssum += red[t + k];
    s2[b * 128 + l] = ssum;
  }
}

// Kernel B: agg partials. One thread per k2 row (l,m), but k2 is staged
// through LDS in 4 j-chunks of 32 floats with coalesced global loads
// (each wave load = 8 full 128B cache lines). LDS row stride = 36 floats
// (144B): 16B-aligned for b128 ops, <=2-way bank aliasing on reads (free).
// Grid 1024 WGs x 256 threads (exactly 4 WGs/CU, 36KB LDS each).
__global__ __launch_bounds__(256) void kB(
    const float* __restrict__ k2, const float* __restrict__ adj,
    const float* __restrict__ s2, float* __restrict__ aggp) {
  __shared__ float lk[256 * 36];   // 36 KB
  __shared__ float part[64];
  const int t = threadIdx.x;
  const int rid0 = blockIdx.x * 256;
  const int rid = rid0 + t;
  const int l = rid0 >> 9;
  const int half = blockIdx.x & 1;

  float dot[16];
#pragma unroll
  for (int b = 0; b < 16; ++b) dot[b] = 0.f;

  for (int jc = 0; jc < 128; jc += 32) {
    __syncthreads();               // protect lk reuse across chunks
    // stage 256 rows x 32 floats, coalesced: 8 float4 per thread
#pragma unroll
    for (int k = 0; k < 8; ++k) {
      const int f = k * 256 + t;          // 0..2047 flat float4 index
      const int row = f >> 3, e4 = f & 7; // row in [0,256), e4 in [0,8)
      const float4 v = *(const float4*)(k2 + (size_t)(rid0 + row) * 128 + jc + e4 * 4);
      *(float4*)(lk + row * 36 + e4 * 4) = v;
    }
    __syncthreads();
    // compute: thread t consumes its own row from LDS
    const float* myrow = lk + t * 36;
#pragma unroll
    for (int e = 0; e < 32; e += 4) {
      const float4 kv = *(const float4*)(myrow + e);
#pragma unroll
      for (int b = 0; b < 16; ++b) {
        const float4 sv = *(const float4*)(s2 + b * 128 + jc + e);  // uniform -> s_load
        dot[b] = fmaf(kv.x, sv.x, dot[b]);
        dot[b] = fmaf(kv.y, sv.y, dot[b]);
        dot[b] = fmaf(kv.z, sv.z, dot[b]);
        dot[b] = fmaf(kv.w, sv.w, dot[b]);
      }
    }
  }

#pragma unroll
  for (int b = 0; b < 16; ++b) {
    float v = adj[(size_t)b * 262144 + rid] * fast_sin(dot[b]);
#pragma unroll
    for (int off = 32; off > 0; off >>= 1) v += __shfl_down(v, off, 64);
    if ((t & 63) == 0) part[(t >> 6) * 16 + b] = v;
  }
  __syncthreads();
  if (t < 16) {
    float ssum = part[t] + part[16 + t] + part[32 + t] + part[48 + t];
    // aggp[half][b][l]
    aggp[half * 8192 + t * 512 + l] = ssum;
  }
}

extern "C" void kernel_launch(void* const* d_in, const int* in_sizes, int n_in,
                              void* d_out, int out_size, void* d_ws, size_t ws_size,
                              hipStream_t stream) {
  const float* y0   = (const float*)d_in[0];  // [16,512]
  const float* bias = (const float*)d_in[1];  // [16,512,1]
  const float* adj  = (const float*)d_in[2];  // [16,512,512]
  const float* k0   = (const float*)d_in[3];  // [128,512,512]
  const float* k1   = (const float*)d_in[4];  // [128,512,128]
  const float* k2   = (const float*)d_in[5];  // [512,512,128]
  float* out = (float*)d_out;                 // [8,16,512] f32

  float* w    = (float*)d_ws;
  float* K0s  = w;               // 65536 floats
  float* K1s  = w + 65536;       // 16384
  float* M    = w + 81920;       // 65536
  float* s2   = w + 147456;      // 2048
  float* ybuf = w + 149504;      // 16384 (2 x 8192, ping-pong)
  float* racc = w + 165888;      // 8192
  float* aggp = w + 174080;      // 16384 (2 halves x [16][512])
  // total: 190464 floats = 762 KB of d_ws

  kPrep1<<<256, 256, 0, stream>>>(k0, K0s);
  kPrep2<<<64, 256, 0, stream>>>(k1, K1s);
  kPrep3<<<256, 256, 0, stream>>>(K0s, K1s, M);

  // init: y = y0, s2 = M*y0  (step = -1 makes ping-pong write ybuf[0])
  kA<<<64, 256, 0, stream>>>(y0, bias, M, aggp, ybuf, racc, s2, out, 0, -1);

  for (int step = 0; step < 8; ++step) {
    for (int stage = 1; stage <= 4; ++stage) {
      kB<<<1024, 256, 0, stream>>>(k2, adj, s2, aggp);
      kA<<<64, 256, 0, stream>>>(y0, bias, M, aggp, ybuf, racc, s2, out, stage, step);
    }
  }
}

// Round 4
// 1326.356 us; speedup vs baseline: 1.7105x; 1.7105x over previous
//
#include <hip/hip_runtime.h>
#include <hip/hip_bf16.h>

typedef float f32x16 __attribute__((ext_vector_type(16)));

#define DT 0.01f

// sin(x) with Cody-Waite reduction mod pi, accurate to ~2e-7 for |x| < ~6000.
__device__ __forceinline__ float fast_sin(float x) {
  const float INVPI = 0.3183098861837907f;
  float n = rintf(x * INVPI);
  int ni = (int)n;
  float r = fmaf(n, -3.140625f, x);          // n*3.140625 exact for |n| < 2^12
  r = fmaf(n, -9.6765358979e-4f, r);         // pi - 3.140625
  float s = r * r;
  float p = fmaf(s, -2.5052108e-8f, 2.7557319e-6f);
  p = fmaf(s, p, -1.9841270e-4f);
  p = fmaf(s, p, 8.3333333e-3f);
  p = fmaf(s, p, -1.6666667e-1f);
  float res = fmaf(r * s, p, r);             // sin(r), |r| <= pi/2
  return (ni & 1) ? -res : res;              // sin(x) = (-1)^n sin(r)
}

// 4x s_load_dwordx16 from a wave-uniform address + waitcnt, all in one asm
// block. Outputs live in SGPRs; consuming FMAs read them as the free scalar
// operand of v_fmac_f32. Dataflow through the asm outputs orders the FMAs
// after the embedded s_waitcnt.
__device__ __forceinline__ void sload4(const float* p, f32x16& a, f32x16& b,
                                       f32x16& c, f32x16& d) {
  asm volatile(
      "s_load_dwordx16 %0, %4, 0\n\t"
      "s_load_dwordx16 %1, %4, 0x40\n\t"
      "s_load_dwordx16 %2, %4, 0x80\n\t"
      "s_load_dwordx16 %3, %4, 0xc0\n\t"
      "s_waitcnt lgkmcnt(0)"
      : "=s"(a), "=s"(b), "=s"(c), "=s"(d)
      : "s"(p));
}

// K0s[h,j] = sum_m k0[h,m,j]   (k0: [128,512,512])
__global__ __launch_bounds__(256) void kPrep1(const float* __restrict__ k0,
                                              float* __restrict__ K0s) {
  int t = blockIdx.x * 256 + threadIdx.x;     // 65536 threads
  int h = t >> 9, j = t & 511;
  const float* p = k0 + (size_t)h * 262144 + j;
  float s = 0.f;
  for (int m = 0; m < 512; ++m) s += p[(size_t)m * 512];
  K0s[t] = s;
}

// K1s[h,j] = sum_m k1[h,m,j]   (k1: [128,512,128])
__global__ __launch_bounds__(256) void kPrep2(const float* __restrict__ k1,
                                              float* __restrict__ K1s) {
  int t = blockIdx.x * 256 + threadIdx.x;     // 16384 threads
  int h = t >> 7, j = t & 127;
  const float* p = k1 + (size_t)h * 65536 + j;
  float s = 0.f;
  for (int m = 0; m < 512; ++m) s += p[(size_t)m * 128];
  K1s[t] = s;
}

// M[l,j] = sum_h K1s[l,h] * K0s[h,j]   ([128,512] = K1s @ K0s)
__global__ __launch_bounds__(256) void kPrep3(const float* __restrict__ K0s,
                                              const float* __restrict__ K1s,
                                              float* __restrict__ M) {
  int t = blockIdx.x * 256 + threadIdx.x;     // 65536 threads
  int l = t >> 9, j = t & 511;
  float s = 0.f;
#pragma unroll 8
  for (int h = 0; h < 128; ++h) s = fmaf(K1s[l * 128 + h], K0s[h * 512 + j], s);
  M[t] = s;
}

// Kernel A: RK4 bookkeeping + s2T = transpose(M * y_stage).
// Grid 64 WGs x 256: WG = (b = blk>>2, quarter q = blk&3).
// stage: 0 = init (y = y0), 1..4 = RK stages. y ping-pongs on step parity.
__global__ __launch_bounds__(256) void kA(
    const float* __restrict__ y0, const float* __restrict__ bias,
    const float* __restrict__ M, const float* __restrict__ aggp,
    float* __restrict__ ybuf,    // [2][16][512]
    float* __restrict__ racc,    // [16][512]
    float* __restrict__ s2T,     // [128][16]  (j-major, b contiguous)
    float* __restrict__ out,     // [8][16][512]
    int stage, int step) {
  __shared__ float ystage[512];
  __shared__ float red[256];
  const int b = blockIdx.x >> 2, q = blockIdx.x & 3, t = threadIdx.x;
  const float* ycur = ybuf + (step & 1) * 8192;
  float* ynext = ybuf + ((step + 1) & 1) * 8192;

  for (int i = t; i < 512; i += 256) {
    const int idx = b * 512 + i;
    const bool own = (i >> 7) == q;   // this WG owns chunk q of row b
    float ys;
    if (stage == 0) {
      ys = y0[idx];
      if (own) ynext[idx] = ys;       // init writes ybuf[0] (step = -1)
    } else {
      const float r = bias[idx] - (aggp[idx] + aggp[8192 + idx]);
      const float yb = ycur[idx];
      if (stage == 1) {
        ys = fmaf(0.5f * DT, r, yb);
        if (own) racc[idx] = r;
      } else if (stage == 2) {
        ys = fmaf(0.5f * DT, r, yb);
        if (own) racc[idx] = racc[idx] + 2.f * r;
      } else if (stage == 3) {
        ys = fmaf(DT, r, yb);
        if (own) racc[idx] = racc[idx] + 2.f * r;
      } else {  // stage 4: finish step
        ys = yb + (DT / 6.f) * (racc[idx] + r);
        if (own) { ynext[idx] = ys; out[step * 8192 + idx] = ys; }
      }
    }
    ystage[i] = ys;
  }
  __syncthreads();

  // s2[b, l] for l in [q*32, q*32+32): 8 threads per dot, 64 j each.
  const int l = q * 32 + (t >> 3), seg = t & 7;
  const float* Mrow = M + l * 512 + seg * 64;
  float p = 0.f;
#pragma unroll 8
  for (int i = 0; i < 64; ++i) p = fmaf(Mrow[i], ystage[seg * 64 + i], p);
  red[t] = p;
  __syncthreads();
  if (seg == 0) {
    float ssum = 0.f;
#pragma unroll
    for (int k = 0; k < 8; ++k) ssum += red[t + k];
    s2T[l * 16 + b] = ssum;   // transposed: b contiguous per j
  }
}

// Kernel B: one thread per k2 row (l,m). k2 is LDS-staged with coalesced
// global loads (full 128B cache lines); s2 arrives as guaranteed SGPR
// broadcasts via inline-asm s_load_dwordx16 of s2T[j][0..16). Inner loop is
// pure v_fmac_f32 v,s,v. Grid 1024 WGs x 256 (4 WGs/CU, 36KB LDS each).
__global__ __launch_bounds__(256) void kB(
    const float* __restrict__ k2, const float* __restrict__ adj,
    const float* __restrict__ s2T, float* __restrict__ aggp) {
  __shared__ float lk[256 * 36];   // 36 KB, stride 36 floats (even bank use)
  __shared__ float part[64];
  const int t = threadIdx.x;
  const int rid0 = blockIdx.x * 256;
  const int rid = rid0 + t;
  const int l = rid0 >> 9;
  const int half = blockIdx.x & 1;

  float dot[16];
#pragma unroll
  for (int b = 0; b < 16; ++b) dot[b] = 0.f;

  for (int c = 0; c < 4; ++c) {
    __syncthreads();
    // stage 256 rows x 32 floats, coalesced: 8 float4 per thread
#pragma unroll
    for (int k = 0; k < 8; ++k) {
      const int f = k * 256 + t;
      const int row = f >> 3, e = f & 7;
      const float4 v = *(const float4*)(k2 + (size_t)(rid0 + row) * 128 + c * 32 + e * 4);
      *(float4*)(lk + row * 36 + e * 4) = v;
    }
    __syncthreads();
    const float* myrow = lk + t * 36;
#pragma unroll
    for (int q = 0; q < 8; ++q) {
      const float4 kv = *(const float4*)(myrow + q * 4);
      f32x16 sa, sb, sc, sd;
      sload4(s2T + (c * 32 + q * 4) * 16, sa, sb, sc, sd);
#pragma unroll
      for (int b = 0; b < 16; ++b) dot[b] = fmaf(sa[b], kv.x, dot[b]);
#pragma unroll
      for (int b = 0; b < 16; ++b) dot[b] = fmaf(sb[b], kv.y, dot[b]);
#pragma unroll
      for (int b = 0; b < 16; ++b) dot[b] = fmaf(sc[b], kv.z, dot[b]);
#pragma unroll
      for (int b = 0; b < 16; ++b) dot[b] = fmaf(sd[b], kv.w, dot[b]);
    }
  }

  // epilogue: adj * sin(dot), wave reduce, write agg partials
#pragma unroll
  for (int b = 0; b < 16; ++b) {
    float v = adj[(size_t)b * 262144 + rid] * fast_sin(dot[b]);
#pragma unroll
    for (int off = 32; off > 0; off >>= 1) v += __shfl_down(v, off, 64);
    if ((t & 63) == 0) part[(t >> 6) * 16 + b] = v;
  }
  __syncthreads();
  if (t < 16) {
    float ssum = part[t] + part[16 + t] + part[32 + t] + part[48 + t];
    aggp[half * 8192 + t * 512 + l] = ssum;   // aggp[half][b][l]
  }
}

extern "C" void kernel_launch(void* const* d_in, const int* in_sizes, int n_in,
                              void* d_out, int out_size, void* d_ws, size_t ws_size,
                              hipStream_t stream) {
  const float* y0   = (const float*)d_in[0];  // [16,512]
  const float* bias = (const float*)d_in[1];  // [16,512,1]
  const float* adj  = (const float*)d_in[2];  // [16,512,512]
  const float* k0   = (const float*)d_in[3];  // [128,512,512]
  const float* k1   = (const float*)d_in[4];  // [128,512,128]
  const float* k2   = (const float*)d_in[5];  // [512,512,128]
  float* out = (float*)d_out;                 // [8,16,512] f32

  float* w    = (float*)d_ws;
  float* K0s  = w;               // 65536 floats
  float* K1s  = w + 65536;       // 16384
  float* M    = w + 81920;       // 65536
  float* s2T  = w + 147456;      // 2048  ([128][16] transposed)
  float* ybuf = w + 149504;      // 16384 (2 x 8192, ping-pong)
  float* racc = w + 165888;      // 8192
  float* aggp = w + 174080;      // 16384 (2 halves x [16][512])
  // total: 190464 floats = 762 KB of d_ws

  kPrep1<<<256, 256, 0, stream>>>(k0, K0s);
  kPrep2<<<64, 256, 0, stream>>>(k1, K1s);
  kPrep3<<<256, 256, 0, stream>>>(K0s, K1s, M);

  // init: y = y0, s2T = (M*y0)^T  (step = -1 makes ping-pong write ybuf[0])
  kA<<<64, 256, 0, stream>>>(y0, bias, M, aggp, ybuf, racc, s2T, out, 0, -1);

  for (int step = 0; step < 8; ++step) {
    for (int stage = 1; stage <= 4; ++stage) {
      kB<<<1024, 256, 0, stream>>>(k2, adj, s2T, aggp);
      kA<<<64, 256, 0, stream>>>(y0, bias, M, aggp, ybuf, racc, s2T, out, stage, step);
    }
  }
}